// Round 1
// 357.561 us; speedup vs baseline: 1.0590x; 1.0590x over previous
//
#include <hip/hip_runtime.h>

// GCNN fused kernel for MI355X (gfx950) — barrier-free GEMM redesign.
// Per block (one sentence, 512 thr): stage A[64][512] bf16 to LDS ONCE in MFMA
// fragment order (XOR-swizzled), fusing the fp32 gate dot-products into the
// staging pass (rep read exactly once). B fragments are read per-wave directly
// from the L2-resident pre-transposed Wt (waves own disjoint 64-col slabs, so
// LDS staging of W deduplicated nothing). K-loop has ZERO barriers; 4 barriers
// total per block. Epilogue: P round-trips LDS (bf16) in one stage for the
// head-row gather.

#define BNK   1280
#define LTOK  64
#define DIN   512
#define DOUT  256
#define TPB   512
#define PSTR  264          // Pin/Psf row stride in bf16 elems (528 B: +16B pad spreads quads)

// LDS layout (bytes):
//   GEMM:     As 4096 fragment-units x 16B @ 0 (65536)
//   epilogue: Pin [64][PSTR] bf16 @ 0 (33792) | Psf @ 33792 (33792)   [union w/ As]
//   gates:    wgi @ 67584 (2048) | wgs @ 69632 (2048) | part @ 71680 (4096)
//   persist:  gld @ 75776 (512) | winl @ 76288 | wsfl @ 76544 | mskl @ 76800
//             hdl @ 77056 | lbl @ 77312   -> total 77568 (2 blocks/CU)
#define SMEM_BYTES 77568

typedef __attribute__((ext_vector_type(4))) float f32x4;
typedef __attribute__((ext_vector_type(8))) short s16x8;

__device__ __forceinline__ unsigned short f2bf(float f) {
  unsigned u = __float_as_uint(f);
  unsigned r = (u + 0x7FFFu + ((u >> 16) & 1u)) >> 16;
  return (unsigned short)r;
}
__device__ __forceinline__ float bf2f(unsigned short h) {
  return __uint_as_float(((unsigned)h) << 16);
}
__device__ __forceinline__ float sigmoidf_(float x) {
  return 1.0f / (1.0f + __expf(-x));
}

// ---------------- kernel 0: W_cat -> bf16, transposed to [cat_col][k] ----------------
__global__ __launch_bounds__(256) void wprep_kernel(const float* __restrict__ W_in,
                                                    const float* __restrict__ W_self,
                                                    unsigned short* __restrict__ Wt) {
  __shared__ float tile[32][33];
  const int t  = threadIdx.x;
  const int c0 = (blockIdx.x & 15) * 32;   // cat col tile
  const int k0 = (blockIdx.x >> 4) * 32;   // k tile
  const float* src = (c0 < DOUT) ? W_in : W_self;
  const int cadj   = (c0 < DOUT) ? c0 : (c0 - DOUT);
  {
    const int kk = t >> 3;
    const int cc = (t & 7) * 4;
    const float4 v = *(const float4*)(src + (size_t)(k0 + kk) * DOUT + cadj + cc);
    tile[kk][cc + 0] = v.x; tile[kk][cc + 1] = v.y;
    tile[kk][cc + 2] = v.z; tile[kk][cc + 3] = v.w;
  }
  __syncthreads();
  {
    const int cc = t >> 3;
    const int kk = (t & 7) * 4;
    ushort4 o;
    o.x = f2bf(tile[kk + 0][cc]); o.y = f2bf(tile[kk + 1][cc]);
    o.z = f2bf(tile[kk + 2][cc]); o.w = f2bf(tile[kk + 3][cc]);
    *(ushort4*)(Wt + (size_t)(c0 + cc) * DIN + k0 + kk) = o;
  }
}

// ---------------- main fused kernel ----------------
__global__ __launch_bounds__(TPB, 4) void gcn_kernel(
    const float* __restrict__ rep,
    const float* __restrict__ adj_mask_in,
    const float* __restrict__ adj_mask_loop,
    const float* __restrict__ maskp,
    const float* __restrict__ b_in,
    const float* __restrict__ w_gate_in,
    const float* __restrict__ b_gate_in,
    const float* __restrict__ w_gate_self,
    const int* __restrict__ arc,
    const int* __restrict__ lab,
    const unsigned short* __restrict__ Wt,
    float* __restrict__ out)
{
  __shared__ __align__(16) char smem[SMEM_BYTES];
  unsigned short* As  = (unsigned short*)(smem);
  unsigned short* Pin = (unsigned short*)(smem);
  unsigned short* Psf = (unsigned short*)(smem + 33792);
  float* wgi  = (float*)(smem + 67584);
  float* wgs  = (float*)(smem + 69632);
  float* part = (float*)(smem + 71680);
  float* gld  = (float*)(smem + 75776);
  float* winl = (float*)(smem + 76288);
  float* wsfl = (float*)(smem + 76544);
  float* mskl = (float*)(smem + 76800);
  int*   hdl  = (int*)(smem + 77056);
  int*   lbl  = (int*)(smem + 77312);

  const int b    = blockIdx.x;     // sentence
  const int t    = threadIdx.x;
  const int wave = t >> 6;
  const int lane = t & 63;
  const int nlo  = lane & 15;
  const int quad = lane >> 4;

  // ---- gate weights to LDS (fp32; sigmoid-sensitive, keep full precision) ----
  wgi[t] = w_gate_in[t];
  wgs[t] = w_gate_self[t];
  __syncthreads();                                     // B1

  // ---- A staging (fragment order, XOR-swizzled) + fused fp32 gate partials ----
  // Thread (r = t>>3, p = t&7) loads rep row r, 16B k-fragments kg = p + 8i.
  // Fragment (kg, r) stored at LDS 16B-unit  (kg>>2)*256 + (kg&3)*64 + (r ^ (kg&7)).
  // kg&7 == p (constant per thread). Consecutive 8 lanes then hit 8 distinct
  // bank-groups on ds_write_b128 (conflict-free); reads permute within a
  // 16-unit block (conflict-free).
  {
    const int r = t >> 3, p = t & 7;
    const float* arow = rep + (size_t)(b * LTOK + r) * DIN;
    float si = 0.f, ss = 0.f;
    #pragma unroll 4
    for (int i = 0; i < 8; ++i) {
      const int kg = p + 8 * i;
      const int kb = kg * 8;
      const float4 v0 = *(const float4*)(arow + kb);
      const float4 v1 = *(const float4*)(arow + kb + 4);
      const float4 g0 = *(const float4*)(wgi + kb);
      const float4 g1 = *(const float4*)(wgi + kb + 4);
      const float4 h0 = *(const float4*)(wgs + kb);
      const float4 h1 = *(const float4*)(wgs + kb + 4);
      si += v0.x*g0.x + v0.y*g0.y + v0.z*g0.z + v0.w*g0.w
          + v1.x*g1.x + v1.y*g1.y + v1.z*g1.z + v1.w*g1.w;
      ss += v0.x*h0.x + v0.y*h0.y + v0.z*h0.z + v0.w*h0.w
          + v1.x*h1.x + v1.y*h1.y + v1.z*h1.z + v1.w*h1.w;
      s16x8 o;
      o[0] = (short)f2bf(v0.x); o[1] = (short)f2bf(v0.y);
      o[2] = (short)f2bf(v0.z); o[3] = (short)f2bf(v0.w);
      o[4] = (short)f2bf(v1.x); o[5] = (short)f2bf(v1.y);
      o[6] = (short)f2bf(v1.z); o[7] = (short)f2bf(v1.w);
      const int u = (kg >> 2) * 256 + (kg & 3) * 64 + (r ^ p);
      *(s16x8*)(As + u * 8) = o;
    }
    part[t * 2 + 0] = si;
    part[t * 2 + 1] = ss;
  }
  __syncthreads();                                     // B2: As + part visible

  // gate partial reduce (waves 0-1 only; overlaps other waves' GEMM start)
  if (t < 128) {
    const int r = t >> 1, g = t & 1;
    float s = 0.f;
    #pragma unroll
    for (int p = 0; p < 8; ++p) s += part[(r * 8 + p) * 2 + g];
    gld[r * 2 + g] = s;
  }

  // ---- barrier-free GEMM: acc[mt][nt] = rows mt*16.., cat cols wave*64 + nt*16.. ----
  f32x4 acc[4][4];
  #pragma unroll
  for (int i = 0; i < 4; ++i)
    #pragma unroll
    for (int j = 0; j < 4; ++j) {
      f32x4 z = {0.f, 0.f, 0.f, 0.f};
      acc[i][j] = z;
    }

  // A-frag lane bases (two kc-parity variants of the XOR swizzle)
  const unsigned short* aeven = As + (quad * 64 + (nlo ^ quad)) * 8;
  const unsigned short* aodd  = As + (quad * 64 + (nlo ^ (quad + 4))) * 8;
  // B-frag lane base: Wt[col = wave*64 + nt*16 + nlo][kc*32 + quad*8 ..]
  const unsigned short* wb = Wt + (size_t)(wave * 64 + nlo) * DIN + quad * 8;

  #pragma unroll
  for (int kc = 0; kc < 16; ++kc) {
    const unsigned short* ab = ((kc & 1) ? aodd : aeven) + kc * 2048;  // kc*256 units
    const unsigned short* wk = wb + kc * 32;
    s16x8 af[4], bf[4];
    #pragma unroll
    for (int mt = 0; mt < 4; ++mt)
      af[mt] = *(const s16x8*)(ab + mt * 128);         // mt*16 units
    #pragma unroll
    for (int nt = 0; nt < 4; ++nt)
      bf[nt] = *(const s16x8*)(wk + nt * 16 * DIN);    // direct from L2-hot Wt
    #pragma unroll
    for (int nt = 0; nt < 4; ++nt)
      #pragma unroll
      for (int mt = 0; mt < 4; ++mt)
        acc[mt][nt] = __builtin_amdgcn_mfma_f32_16x16x32_bf16(af[mt], bf[nt], acc[mt][nt], 0, 0, 0);
  }

  __syncthreads();                                     // B3: af reads done, gld final

  // per-row epilogue scalars (head gather of raw gate + sigmoid + masks)
  if (t < LTOK) {
    const int m  = b * LTOK + t;
    const int hd = arc[2 * m + 1];   // head token position (sent == b by construction)
    const int lb = lab[m];
    const float am = adj_mask_in[m];
    const float al = adj_mask_loop[m];
    winl[t] = sigmoidf_(gld[hd * 2 + 0] + b_gate_in[lb]) * am * am;
    wsfl[t] = sigmoidf_(gld[t * 2 + 1]) * al * al;
    mskl[t] = maskp[m];
    hdl[t]  = hd;
    lbl[t]  = lb;
  }

  // P -> LDS (bf16, single stage; As region is dead). waves 0-3: P_in, 4-7: P_self.
  {
    unsigned short* dst = (wave < 4) ? Pin : Psf;
    const int cb = (wave & 3) * 64;
    #pragma unroll
    for (int mt = 0; mt < 4; ++mt)
      #pragma unroll
      for (int nt = 0; nt < 4; ++nt)
        #pragma unroll
        for (int rr = 0; rr < 4; ++rr) {
          const int row = mt * 16 + quad * 4 + rr;     // C/D: row = quad*4 + reg
          const int col = cb + nt * 16 + nlo;          // C/D: col = lane&15
          dst[row * PSTR + col] = f2bf(acc[mt][nt][rr]);
        }
  }
  __syncthreads();                                     // B4

  // out = relu((Pin[hd] + b_in[lb]) * w_in + Psf[row] * w_self) * mask
  #pragma unroll
  for (int i = 0; i < 8; ++i) {
    const int row = i * 8 + wave;                      // each wave: 8 rows
    const int cl  = (t & 63) * 4;                      // lane covers 256 cols as float4
    const int hd  = hdl[row];
    const int lb  = lbl[row];
    const float wi = winl[row], ws = wsfl[row], mk = mskl[row];
    const float4  bi = *(const float4*)(b_in + lb * DOUT + cl);
    const ushort4 pi = *(const ushort4*)(Pin + hd * PSTR + cl);
    const ushort4 ps = *(const ushort4*)(Psf + row * PSTR + cl);
    float4 v;
    v.x = (bf2f(pi.x) + bi.x) * wi + bf2f(ps.x) * ws;
    v.y = (bf2f(pi.y) + bi.y) * wi + bf2f(ps.y) * ws;
    v.z = (bf2f(pi.z) + bi.z) * wi + bf2f(ps.z) * ws;
    v.w = (bf2f(pi.w) + bi.w) * wi + bf2f(ps.w) * ws;
    v.x = fmaxf(v.x, 0.f) * mk; v.y = fmaxf(v.y, 0.f) * mk;
    v.z = fmaxf(v.z, 0.f) * mk; v.w = fmaxf(v.w, 0.f) * mk;
    *(float4*)(out + (size_t)(b * LTOK + row) * DOUT + cl) = v;
  }
}

extern "C" void kernel_launch(void* const* d_in, const int* in_sizes, int n_in,
                              void* d_out, int out_size, void* d_ws, size_t ws_size,
                              hipStream_t stream) {
  const float* rep           = (const float*)d_in[0];
  const float* adj_mask_in   = (const float*)d_in[1];
  const float* adj_mask_loop = (const float*)d_in[2];
  const float* mask          = (const float*)d_in[3];
  const float* W_in          = (const float*)d_in[4];
  const float* b_in          = (const float*)d_in[5];
  const float* W_gate_in     = (const float*)d_in[6];
  const float* b_gate_in     = (const float*)d_in[7];
  const float* W_self        = (const float*)d_in[8];
  const float* W_gate_self   = (const float*)d_in[9];
  const int*   arc           = (const int*)d_in[10];
  const int*   lab           = (const int*)d_in[11];
  float* out = (float*)d_out;
  unsigned short* Wt = (unsigned short*)d_ws;   // [512][512] bf16, 512 KB

  wprep_kernel<<<256, 256, 0, stream>>>(W_in, W_self, Wt);
  gcn_kernel<<<BNK, TPB, 0, stream>>>(rep, adj_mask_in, adj_mask_loop, mask, b_in,
                                      W_gate_in, b_gate_in, W_gate_self, arc, lab, Wt, out);
}

// Round 2
// 353.013 us; speedup vs baseline: 1.0727x; 1.0129x over previous
//
#include <hip/hip_runtime.h>

// GCNN fused kernel for MI355X (gfx950) — register-pipelined GEMM, 16 waves.
// Round-1 post-mortem: launch_bounds(512,4) -> 128 unified regs; acc[4][4]=64 AGPR
// left 64 VGPRs -> compiler couldn't prefetch B-frags -> full L2 latency exposed
// per K-step. Fix: reshard N across 16 waves (per-wave tile 64x32, acc=32 AGPR),
// spend the freed regs on an explicit 2-step-ahead B-fragment register pipeline.
// A stays LDS-resident (fragment-ordered, XOR-swizzled), staged once with fused
// fp32 gate dot-products (shuffle-reduced, no LDS partials). 4 barriers total.

#define BNK   1280
#define LTOK  64
#define DIN   512
#define DOUT  256
#define TPB   1024
#define PSTR  264          // Pin/Psf row stride in bf16 elems (528 B pad spreads quads)

// LDS layout (bytes):
//   GEMM:     As 4096 fragment-units x 16B @ 0 (65536)
//   epilogue: Pin [64][PSTR] bf16 @ 0 (33792) | Psf @ 33792 (33792)  [union w/ As]
//   gates:    wgi @ 67584 (2048) | wgs @ 69632 (2048)
//   persist:  gld @ 71680 (512) | winl @ 72192 | wsfl @ 72448 | mskl @ 72704
//             hdl @ 72960 | lbl @ 73216  -> total 73472
#define SMEM_BYTES 73472

typedef __attribute__((ext_vector_type(4))) float f32x4;
typedef __attribute__((ext_vector_type(8))) short s16x8;

__device__ __forceinline__ unsigned short f2bf(float f) {
  unsigned u = __float_as_uint(f);
  unsigned r = (u + 0x7FFFu + ((u >> 16) & 1u)) >> 16;
  return (unsigned short)r;
}
__device__ __forceinline__ float bf2f(unsigned short h) {
  return __uint_as_float(((unsigned)h) << 16);
}
__device__ __forceinline__ float sigmoidf_(float x) {
  return 1.0f / (1.0f + __expf(-x));
}

// ---------------- kernel 0: W_cat -> bf16, transposed to [cat_col][k] ----------------
__global__ __launch_bounds__(256) void wprep_kernel(const float* __restrict__ W_in,
                                                    const float* __restrict__ W_self,
                                                    unsigned short* __restrict__ Wt) {
  __shared__ float tile[32][33];
  const int t  = threadIdx.x;
  const int c0 = (blockIdx.x & 15) * 32;   // cat col tile
  const int k0 = (blockIdx.x >> 4) * 32;   // k tile
  const float* src = (c0 < DOUT) ? W_in : W_self;
  const int cadj   = (c0 < DOUT) ? c0 : (c0 - DOUT);
  {
    const int kk = t >> 3;
    const int cc = (t & 7) * 4;
    const float4 v = *(const float4*)(src + (size_t)(k0 + kk) * DOUT + cadj + cc);
    tile[kk][cc + 0] = v.x; tile[kk][cc + 1] = v.y;
    tile[kk][cc + 2] = v.z; tile[kk][cc + 3] = v.w;
  }
  __syncthreads();
  {
    const int cc = t >> 3;
    const int kk = (t & 7) * 4;
    ushort4 o;
    o.x = f2bf(tile[kk + 0][cc]); o.y = f2bf(tile[kk + 1][cc]);
    o.z = f2bf(tile[kk + 2][cc]); o.w = f2bf(tile[kk + 3][cc]);
    *(ushort4*)(Wt + (size_t)(c0 + cc) * DIN + k0 + kk) = o;
  }
}

// ---------------- main fused kernel ----------------
__global__ __launch_bounds__(TPB, 4) void gcn_kernel(
    const float* __restrict__ rep,
    const float* __restrict__ adj_mask_in,
    const float* __restrict__ adj_mask_loop,
    const float* __restrict__ maskp,
    const float* __restrict__ b_in,
    const float* __restrict__ w_gate_in,
    const float* __restrict__ b_gate_in,
    const float* __restrict__ w_gate_self,
    const int* __restrict__ arc,
    const int* __restrict__ lab,
    const unsigned short* __restrict__ Wt,
    float* __restrict__ out)
{
  __shared__ __align__(16) char smem[SMEM_BYTES];
  unsigned short* As  = (unsigned short*)(smem);
  unsigned short* Pin = (unsigned short*)(smem);
  unsigned short* Psf = (unsigned short*)(smem + 33792);
  float* wgi  = (float*)(smem + 67584);
  float* wgs  = (float*)(smem + 69632);
  float* gld  = (float*)(smem + 71680);
  float* winl = (float*)(smem + 72192);
  float* wsfl = (float*)(smem + 72448);
  float* mskl = (float*)(smem + 72704);
  int*   hdl  = (int*)(smem + 72960);
  int*   lbl  = (int*)(smem + 73216);

  const int b    = blockIdx.x;     // sentence
  const int t    = threadIdx.x;
  const int w    = t >> 6;         // wave 0..15 (owns cat cols w*32 .. w*32+31)
  const int lane = t & 63;
  const int nlo  = lane & 15;
  const int quad = lane >> 4;

  // ---- gate weights to LDS (fp32; sigmoid-sensitive, keep full precision) ----
  if (t < DIN) {
    wgi[t] = w_gate_in[t];
    wgs[t] = w_gate_self[t];
  }
  __syncthreads();                                     // B1

  // ---- A staging (fragment order, XOR-swizzled) + fused fp32 gate partials ----
  // Thread (r = t>>4, p = t&15) loads rep row r, 16B k-fragments kg = p + 16i.
  // Fragment (kg, r) -> LDS 16B-unit (kg>>2)*256 + (kg&3)*64 + (r ^ (kg&7)).
  // kg&7 == p&7 (constant per thread).
  {
    const int r = t >> 4, p = t & 15;
    const float* arow = rep + (size_t)(b * LTOK + r) * DIN;
    float si = 0.f, ss = 0.f;
    #pragma unroll
    for (int i = 0; i < 4; ++i) {
      const int kg = p + 16 * i;
      const int kb = kg * 8;
      const float4 v0 = *(const float4*)(arow + kb);
      const float4 v1 = *(const float4*)(arow + kb + 4);
      const float4 g0 = *(const float4*)(wgi + kb);
      const float4 g1 = *(const float4*)(wgi + kb + 4);
      const float4 h0 = *(const float4*)(wgs + kb);
      const float4 h1 = *(const float4*)(wgs + kb + 4);
      si += v0.x*g0.x + v0.y*g0.y + v0.z*g0.z + v0.w*g0.w
          + v1.x*g1.x + v1.y*g1.y + v1.z*g1.z + v1.w*g1.w;
      ss += v0.x*h0.x + v0.y*h0.y + v0.z*h0.z + v0.w*h0.w
          + v1.x*h1.x + v1.y*h1.y + v1.z*h1.z + v1.w*h1.w;
      s16x8 o;
      o[0] = (short)f2bf(v0.x); o[1] = (short)f2bf(v0.y);
      o[2] = (short)f2bf(v0.z); o[3] = (short)f2bf(v0.w);
      o[4] = (short)f2bf(v1.x); o[5] = (short)f2bf(v1.y);
      o[6] = (short)f2bf(v1.z); o[7] = (short)f2bf(v1.w);
      const int u = ((p >> 2) + 4 * i) * 256 + (p & 3) * 64 + (r ^ (p & 7));
      *(s16x8*)(As + u * 8) = o;
    }
    // gate reduce across the 16 lanes of this row (lanes differ only in p)
    #pragma unroll
    for (int off = 1; off < 16; off <<= 1) {
      si += __shfl_xor(si, off, 64);
      ss += __shfl_xor(ss, off, 64);
    }
    if (p == 0) {
      gld[r * 2 + 0] = si;
      gld[r * 2 + 1] = ss;
    }
  }
  __syncthreads();                                     // B2: As visible

  // ---- barrier-free GEMM with 2-step-ahead B register pipeline ----
  // acc[mt][nt]: rows mt*16.., cat cols w*32 + nt*16..
  f32x4 acc[4][2];
  #pragma unroll
  for (int i = 0; i < 4; ++i)
    #pragma unroll
    for (int j = 0; j < 2; ++j) {
      f32x4 z = {0.f, 0.f, 0.f, 0.f};
      acc[i][j] = z;
    }

  // A-frag lane bases (two kc-parity variants of the XOR swizzle)
  const unsigned short* aeven = As + (quad * 64 + (nlo ^ quad)) * 8;
  const unsigned short* aodd  = As + (quad * 64 + (nlo ^ (quad + 4))) * 8;
  // B-frag lane bases: Wt[col = w*32 + nt*16 + nlo][kc*32 + quad*8 ..]
  const unsigned short* wb0 = Wt + (size_t)(w * 32 + nlo) * DIN + quad * 8;
  const unsigned short* wb1 = wb0 + 16 * DIN;

  s16x8 bfr[3][2];
  bfr[0][0] = *(const s16x8*)(wb0);
  bfr[0][1] = *(const s16x8*)(wb1);
  bfr[1][0] = *(const s16x8*)(wb0 + 32);
  bfr[1][1] = *(const s16x8*)(wb1 + 32);

  #pragma unroll
  for (int kc = 0; kc < 16; ++kc) {
    if (kc + 2 < 16) {                       // issue loads 2 K-steps ahead
      bfr[(kc + 2) % 3][0] = *(const s16x8*)(wb0 + (kc + 2) * 32);
      bfr[(kc + 2) % 3][1] = *(const s16x8*)(wb1 + (kc + 2) * 32);
    }
    const unsigned short* ab = ((kc & 1) ? aodd : aeven) + kc * 2048;
    s16x8 af[4];
    #pragma unroll
    for (int mt = 0; mt < 4; ++mt)
      af[mt] = *(const s16x8*)(ab + mt * 128);
    __builtin_amdgcn_s_setprio(1);
    #pragma unroll
    for (int nt = 0; nt < 2; ++nt)
      #pragma unroll
      for (int mt = 0; mt < 4; ++mt)
        acc[mt][nt] = __builtin_amdgcn_mfma_f32_16x16x32_bf16(af[mt], bfr[kc % 3][nt], acc[mt][nt], 0, 0, 0);
    __builtin_amdgcn_s_setprio(0);
  }

  __syncthreads();                                     // B3: af reads done, gld final

  // per-row epilogue scalars (head gather of raw gate + sigmoid + masks)
  if (t < LTOK) {
    const int m  = b * LTOK + t;
    const int hd = arc[2 * m + 1];   // head token position (sent == b by construction)
    const int lb = lab[m];
    const float am = adj_mask_in[m];
    const float al = adj_mask_loop[m];
    winl[t] = sigmoidf_(gld[hd * 2 + 0] + b_gate_in[lb]) * am * am;
    wsfl[t] = sigmoidf_(gld[t * 2 + 1]) * al * al;
    mskl[t] = maskp[m];
    hdl[t]  = hd;
    lbl[t]  = lb;
  }

  // P -> LDS (bf16, single stage; As region is dead). waves 0-7: P_in, 8-15: P_self.
  {
    unsigned short* dst = (w < 8) ? Pin : Psf;
    const int cb = (w & 7) * 32;
    #pragma unroll
    for (int mt = 0; mt < 4; ++mt)
      #pragma unroll
      for (int nt = 0; nt < 2; ++nt)
        #pragma unroll
        for (int rr = 0; rr < 4; ++rr) {
          const int row = mt * 16 + quad * 4 + rr;     // C/D: row = quad*4 + reg
          const int col = cb + nt * 16 + nlo;          // C/D: col = lane&15
          dst[row * PSTR + col] = f2bf(acc[mt][nt][rr]);
        }
  }
  __syncthreads();                                     // B4

  // out = relu((Pin[hd] + b_in[lb]) * w_in + Psf[row] * w_self) * mask
  #pragma unroll
  for (int i = 0; i < 4; ++i) {
    const int q   = i * TPB + t;
    const int row = q >> 6;                            // 64 float4-chunks per row
    const int cl  = (q & 63) * 4;
    const int hd  = hdl[row];
    const int lb  = lbl[row];
    const float wi = winl[row], ws = wsfl[row], mk = mskl[row];
    const float4  bi = *(const float4*)(b_in + lb * DOUT + cl);
    const ushort4 pi = *(const ushort4*)(Pin + hd * PSTR + cl);
    const ushort4 ps = *(const ushort4*)(Psf + row * PSTR + cl);
    float4 v;
    v.x = (bf2f(pi.x) + bi.x) * wi + bf2f(ps.x) * ws;
    v.y = (bf2f(pi.y) + bi.y) * wi + bf2f(ps.y) * ws;
    v.z = (bf2f(pi.z) + bi.z) * wi + bf2f(ps.z) * ws;
    v.w = (bf2f(pi.w) + bi.w) * wi + bf2f(ps.w) * ws;
    v.x = fmaxf(v.x, 0.f) * mk; v.y = fmaxf(v.y, 0.f) * mk;
    v.z = fmaxf(v.z, 0.f) * mk; v.w = fmaxf(v.w, 0.f) * mk;
    *(float4*)(out + (size_t)(b * LTOK + row) * DOUT + cl) = v;
  }
}

extern "C" void kernel_launch(void* const* d_in, const int* in_sizes, int n_in,
                              void* d_out, int out_size, void* d_ws, size_t ws_size,
                              hipStream_t stream) {
  const float* rep           = (const float*)d_in[0];
  const float* adj_mask_in   = (const float*)d_in[1];
  const float* adj_mask_loop = (const float*)d_in[2];
  const float* mask          = (const float*)d_in[3];
  const float* W_in          = (const float*)d_in[4];
  const float* b_in          = (const float*)d_in[5];
  const float* W_gate_in     = (const float*)d_in[6];
  const float* b_gate_in     = (const float*)d_in[7];
  const float* W_self        = (const float*)d_in[8];
  const float* W_gate_self   = (const float*)d_in[9];
  const int*   arc           = (const int*)d_in[10];
  const int*   lab           = (const int*)d_in[11];
  float* out = (float*)d_out;
  unsigned short* Wt = (unsigned short*)d_ws;   // [512][512] bf16, 512 KB

  wprep_kernel<<<256, 256, 0, stream>>>(W_in, W_self, Wt);
  gcn_kernel<<<BNK, TPB, 0, stream>>>(rep, adj_mask_in, adj_mask_loop, mask, b_in,
                                      W_gate_in, b_gate_in, W_gate_self, arc, lab, Wt, out);
}